// Round 17
// baseline (237.706 us; speedup 1.0000x reference)
//
#include <hip/hip_runtime.h>

#define N_KSV 37248
#define N_KW  36864
#define K5_BLOCKS 582     // N_KSV / 64
#define XP_BLOCKS 1024    // 16 b x 64 stripes(256 pos)

typedef float f32x4 __attribute__((ext_vector_type(4)));
typedef short short8 __attribute__((ext_vector_type(8)));
typedef short short4v __attribute__((ext_vector_type(4)));
typedef __bf16 bf16x8 __attribute__((ext_vector_type(8)));

__device__ inline short f2bs(float f) {
  unsigned u = __builtin_bit_cast(unsigned, f);
  u += 0x7fffu + ((u >> 16) & 1u);
  return (short)(u >> 16);
}

__device__ inline f32x4 ntl4(const float* p) {
  return __builtin_nontemporal_load(reinterpret_cast<const f32x4*>(p));
}

__device__ inline f32x4 mfma16(short8 a, short8 b, f32x4 c) {
  return __builtin_amdgcn_mfma_f32_16x16x32_bf16(
      __builtin_bit_cast(bf16x8, a), __builtin_bit_cast(bf16x8, b), c, 0, 0, 0);
}

// ---------------- hypernet small chain (fp32) ----------------
__global__ void k_h0(const float* __restrict__ lat, const float* __restrict__ w,
                     const float* __restrict__ bias, float* __restrict__ h0) {
  int j = blockIdx.x * 256 + threadIdx.x;   // < 512
  int b = blockIdx.y;
  const float* lp = lat + b * 512;
  float acc = bias[j];
#pragma unroll 16
  for (int k = 0; k < 512; ++k) acc = fmaf(lp[k], w[k * 512 + j], acc);
  h0[b * 512 + j] = acc;
}

__global__ void k_t1(const float* __restrict__ h0, const float* __restrict__ w,
                     const float* __restrict__ bias, float* __restrict__ t1) {
  int j = blockIdx.x * 256 + threadIdx.x;   // < 1024
  int b = blockIdx.y;
  const float* hp = h0 + b * 512;
  float acc = bias[j];
#pragma unroll 16
  for (int k = 0; k < 512; ++k) acc = fmaf(hp[k], w[k * 1024 + j], acc);
  t1[b * 1024 + j] = fmaxf(acc, 0.f);
}

// writes hxT bf16 [16 batches][1536 k] rows 0..511 (the A operand of k5)
__global__ void k_h(const float* __restrict__ h0, const float* __restrict__ t1,
                    const float* __restrict__ w, const float* __restrict__ bias,
                    float* __restrict__ h, short* __restrict__ hxT) {
  int j = blockIdx.x * 256 + threadIdx.x;   // < 512
  int b = blockIdx.y;
  const float* tp = t1 + b * 1024;
  float acc = bias[j];
#pragma unroll 16
  for (int k = 0; k < 1024; ++k) acc = fmaf(tp[k], w[k * 512 + j], acc);
  float v = acc + h0[b * 512 + j];
  h[b * 512 + j] = v;
  hxT[b * 1536 + j] = f2bs(v);
}

__global__ void k_t2(const float* __restrict__ h, const float* __restrict__ w,
                     const float* __restrict__ bias, short* __restrict__ hxT) {
  int j = blockIdx.x * 256 + threadIdx.x;   // < 1024
  int b = blockIdx.y;
  const float* hp = h + b * 512;
  float acc = bias[j];
#pragma unroll 16
  for (int k = 0; k < 512; ++k) acc = fmaf(hp[k], w[k * 1024 + j], acc);
  hxT[b * 1536 + 512 + j] = f2bs(fmaxf(acc, 0.f));   // rows 512..1535
}

// ---------------- fused dispatch: k5 fat GEMM (blocks < 582) + x-prep (rest) ----------------
// k5 part: unchanged R12 structure, at the measured d_in-read floor.
// x-prep part: converts x[b][64ch][16384] fp32 -> xTw bf16 in MFMA fragment
// order [b][tile(256)][cg(8)][p(64)][j(8)] so k_dyna can read B-fragments
// directly from global (16B/lane coalesced) and skip staging entirely.
// Running x-prep INSIDE the k5 dispatch overlaps x's 67 MB read with the
// 229 MB weight stream; xTw is written with PLAIN stores (wants L2/L3-hot).
#define LOADB(dst, ktv) { \
    const float* bp_ = ((ktv) < 16) ? (wsp + (size_t)((ktv) * 32) * N_KSV) \
                                    : (w2p + (size_t)((ktv) * 32 - 512) * N_KSV); \
    dst[0] = *reinterpret_cast<const f32x4*>(bp_); \
    dst[1] = *reinterpret_cast<const f32x4*>(bp_ + (size_t)1 * N_KSV); \
    dst[2] = *reinterpret_cast<const f32x4*>(bp_ + (size_t)2 * N_KSV); \
    dst[3] = *reinterpret_cast<const f32x4*>(bp_ + (size_t)3 * N_KSV); \
    dst[4] = *reinterpret_cast<const f32x4*>(bp_ + (size_t)4 * N_KSV); \
    dst[5] = *reinterpret_cast<const f32x4*>(bp_ + (size_t)5 * N_KSV); \
    dst[6] = *reinterpret_cast<const f32x4*>(bp_ + (size_t)6 * N_KSV); \
    dst[7] = *reinterpret_cast<const f32x4*>(bp_ + (size_t)7 * N_KSV); }

#define LOADA(dst, ktv) \
    dst = *reinterpret_cast<const short8*>(apb + (ktv) * 32);

#define COMPUTE(bsrc, asrc) { \
    _Pragma("unroll") \
    for (int t = 0; t < 4; ++t) { \
      short8 bf_; \
      bf_[0] = f2bs(bsrc[0][t]); bf_[1] = f2bs(bsrc[1][t]); \
      bf_[2] = f2bs(bsrc[2][t]); bf_[3] = f2bs(bsrc[3][t]); \
      bf_[4] = f2bs(bsrc[4][t]); bf_[5] = f2bs(bsrc[5][t]); \
      bf_[6] = f2bs(bsrc[6][t]); bf_[7] = f2bs(bsrc[7][t]); \
      acc[t] = mfma16(asrc, bf_, acc[t]); \
    } }

__global__ __launch_bounds__(256, 4) void k5_fused(
    const float* __restrict__ wsm, const float* __restrict__ w2,
    const short* __restrict__ hxT, const float* __restrict__ b2,
    const float* __restrict__ x,
    float* __restrict__ ksv, short* __restrict__ kwb,
    short* __restrict__ xTw) {
  __shared__ __align__(16) char smem[32768];
  const int tid = threadIdx.x;

  if (blockIdx.x < K5_BLOCKS) {
    // ================= k5: ksv[16][N] = hx[16][1536] @ W =================
    f32x4 (*red)[64][4] = reinterpret_cast<f32x4 (*)[64][4]>(smem);  // 12 KB
    const int wv = tid >> 6;
    const int lane = tid & 63;
    const int col0 = blockIdx.x * 64;
    const int l15 = lane & 15;
    const int lg = lane >> 4;

    const float* wsp = wsm + (size_t)(lg * 8) * N_KSV + col0 + l15 * 4;
    const float* w2p = w2 + (size_t)(lg * 8) * N_KSV + col0 + l15 * 4;
    const short* apb = hxT + l15 * 1536 + lg * 8;

    f32x4 acc[4];
#pragma unroll
    for (int t = 0; t < 4; ++t) acc[t] = (f32x4){0.f, 0.f, 0.f, 0.f};

    const int kt0 = wv * 12;
    f32x4 bA[8], bB[8];
    short8 aA, aB;
    LOADB(bA, kt0);
    LOADA(aA, kt0);

#pragma unroll
    for (int s = 0; s < 12; ++s) {
      if (s + 1 < 12) {
        if ((s & 1) == 0) {
          LOADB(bB, kt0 + s + 1);
          LOADA(aB, kt0 + s + 1);
        } else {
          LOADB(bA, kt0 + s + 1);
          LOADA(aA, kt0 + s + 1);
        }
      }
      if ((s & 1) == 0) COMPUTE(bA, aA) else COMPUTE(bB, aB)
    }

    if (wv > 0) {
#pragma unroll
      for (int t = 0; t < 4; ++t) red[wv - 1][lane][t] = acc[t];
    }
    __syncthreads();
    if (wv != 0) return;

#pragma unroll
    for (int t = 0; t < 4; ++t) {
      acc[t] += red[0][lane][t];
      acc[t] += red[1][lane][t];
      acc[t] += red[2][lane][t];
    }

    const int m0 = lg * 4;
#pragma unroll
    for (int t = 0; t < 4; ++t) {
      const int col = col0 + l15 * 4 + t;
      const float bias = b2[col];
#pragma unroll
      for (int r = 0; r < 4; ++r) {
        float s = acc[t][r] + bias;
        ksv[(size_t)(m0 + r) * N_KSV + col] = s;
        if (col < N_KW)
          kwb[(size_t)(m0 + r) * N_KW + col] = f2bs(s);
      }
    }
  } else {
    // ================= x-prep: x -> xTw (bf16 fragment order) =================
    short* lsh = reinterpret_cast<short*>(smem);   // [8 cg][256 p][8 j] = 32 KB
    const int bx = blockIdx.x - K5_BLOCKS;
    const int b = bx >> 6;
    const int s = bx & 63;
    const int pos0 = s << 8;

    const float* xb = x + ((size_t)b << 20);
    const int cc = (tid >> 3) * 2;        // channel pair 0,2,..,62
    const int pc = (tid & 7) * 32;        // 32-pos chunk
    const float* r0 = xb + (size_t)cc * 16384 + pos0 + pc;
    const float* r1 = r0 + 16384;

    f32x4 v0[8], v1[8];
#pragma unroll
    for (int i = 0; i < 8; ++i) v0[i] = ntl4(r0 + i * 4);
#pragma unroll
    for (int i = 0; i < 8; ++i) v1[i] = ntl4(r1 + i * 4);

    const int cg = cc >> 3;
    const int j = cc & 7;                 // even
#pragma unroll
    for (int p = 0; p < 32; ++p) {
      int pk = (int)(unsigned short)f2bs(v0[p >> 2][p & 3]) |
               ((int)f2bs(v1[p >> 2][p & 3]) << 16);
      *reinterpret_cast<int*>(&lsh[cg * 2048 + (pc + p) * 8 + j]) = pk;
    }
    __syncthreads();

    // write 4 tiles x [cg][p64][j] = 16384 shorts, fully linear
    short* dst = xTw + (size_t)(b * 256 + s * 4) * 4096;
#pragma unroll
    for (int i = 0; i < 8; ++i) {
      int q = i * 2048 + tid * 8;
      int t_ = q >> 12, r_ = q & 4095;
      int cg_ = r_ >> 9, rem = r_ & 511;
      *reinterpret_cast<short8*>(dst + q) =
          *reinterpret_cast<const short8*>(&lsh[cg_ * 2048 + t_ * 512 + rem]);
    }
  }
}

// ---------------- fused dyna block: B-fragments direct from global xTw ----------------
__device__ inline int h_idx(int p, int c) {
  return p * 128 + ((((c >> 3) ^ (p & 7)) << 3) | (c & 7));
}

__global__ __launch_bounds__(256) void k_dyna(const short* __restrict__ xTw,
                                              const short* __restrict__ kwb,
                                              const float* __restrict__ ksv,
                                              float* __restrict__ out) {
  __shared__ __align__(16) short lds[16384];  // h1:0..8191  h2:8192..16383
  short* h1 = lds;
  short* h2 = lds + 8192;
  float* sout = reinterpret_cast<float*>(h1);  // h1 dead after layer 2

  const int tid = threadIdx.x;
  const int lane = tid & 63;
  const int w = tid >> 6;        // wave 0..3
  const int l15 = lane & 15;
  const int lg = lane >> 4;      // 0..3

  const int b = blockIdx.x >> 8;
  const int tg = blockIdx.x & 255;
  const int pos0 = tg << 6;

  const short* xw = xTw + (size_t)(b * 256 + tg) * 4096;  // [cg][p64][j]
  const short* kw = kwb + b * N_KW;
  const float* bias = ksv + (size_t)b * N_KSV + N_KW;     // b_in|b_mid|b_out|b_sh

  // ---- layer 1: h1 = relu(Kin(128x64) @ x + b_in); x frags from global ----
  short8 a1[2][2];
#pragma unroll
  for (int mt = 0; mt < 2; ++mt)
#pragma unroll
    for (int kf = 0; kf < 2; ++kf)
      a1[mt][kf] = *reinterpret_cast<const short8*>(
          kw + (w * 32 + mt * 16 + l15) * 64 + kf * 32 + lg * 8);

  f32x4 zero = {0.f, 0.f, 0.f, 0.f};
  f32x4 acc1[2][4];
#pragma unroll
  for (int mt = 0; mt < 2; ++mt)
#pragma unroll
    for (int nt = 0; nt < 4; ++nt) acc1[mt][nt] = zero;

#pragma unroll
  for (int nt = 0; nt < 4; ++nt) {
    short8 b0 = *reinterpret_cast<const short8*>(
        xw + lg * 512 + (nt * 16 + l15) * 8);
    short8 b1 = *reinterpret_cast<const short8*>(
        xw + (4 + lg) * 512 + (nt * 16 + l15) * 8);
#pragma unroll
    for (int mt = 0; mt < 2; ++mt) {
      acc1[mt][nt] = mfma16(a1[mt][0], b0, acc1[mt][nt]);
      acc1[mt][nt] = mfma16(a1[mt][1], b1, acc1[mt][nt]);
    }
  }
#pragma unroll
  for (int mt = 0; mt < 2; ++mt) {
    int ch0 = w * 32 + mt * 16 + lg * 4;
    f32x4 bv = *reinterpret_cast<const f32x4*>(bias + ch0);
#pragma unroll
    for (int nt = 0; nt < 4; ++nt) {
      int p = nt * 16 + l15;
      short4v hv;
#pragma unroll
      for (int jj = 0; jj < 4; ++jj)
        hv[jj] = f2bs(fmaxf(acc1[mt][nt][jj] + bv[jj], 0.f));
      *reinterpret_cast<short4v*>(&h1[h_idx(p, ch0)]) = hv;
    }
  }
  __syncthreads();

  // ---- layer 2: h2 = relu(Kmid(128x128) @ h1 + b_mid) ----
  short8 a2[2][4];
#pragma unroll
  for (int mt = 0; mt < 2; ++mt)
#pragma unroll
    for (int kf = 0; kf < 4; ++kf)
      a2[mt][kf] = *reinterpret_cast<const short8*>(
          kw + 8192 + (w * 32 + mt * 16 + l15) * 128 + kf * 32 + lg * 8);

  f32x4 acc2[2][4];
#pragma unroll
  for (int mt = 0; mt < 2; ++mt)
#pragma unroll
    for (int nt = 0; nt < 4; ++nt) acc2[mt][nt] = zero;

#pragma unroll
  for (int nt = 0; nt < 4; ++nt) {
    int p = nt * 16 + l15;
    short8 bb[4];
#pragma unroll
    for (int kf = 0; kf < 4; ++kf)
      bb[kf] = *reinterpret_cast<const short8*>(&h1[h_idx(p, kf * 32 + lg * 8)]);
#pragma unroll
    for (int mt = 0; mt < 2; ++mt)
#pragma unroll
      for (int kf = 0; kf < 4; ++kf)
        acc2[mt][nt] = mfma16(a2[mt][kf], bb[kf], acc2[mt][nt]);
  }
#pragma unroll
  for (int mt = 0; mt < 2; ++mt) {
    int ch0 = w * 32 + mt * 16 + lg * 4;
    f32x4 bv = *reinterpret_cast<const f32x4*>(bias + 128 + ch0);
#pragma unroll
    for (int nt = 0; nt < 4; ++nt) {
      int p = nt * 16 + l15;
      short4v hv;
#pragma unroll
      for (int jj = 0; jj < 4; ++jj)
        hv[jj] = f2bs(fmaxf(acc2[mt][nt][jj] + bv[jj], 0.f));
      *reinterpret_cast<short4v*>(&h2[h_idx(p, ch0)]) = hv;
    }
  }
  __syncthreads();
  // h1 fully consumed -> sout may overwrite it.

  // ---- layer 3: Kout(64x128) @ h2 + Ksh(64x64) @ x + biases -> sout ----
  short8 a3[4], ash[2];
#pragma unroll
  for (int kf = 0; kf < 4; ++kf)
    a3[kf] = *reinterpret_cast<const short8*>(
        kw + 24576 + (w * 16 + l15) * 128 + kf * 32 + lg * 8);
#pragma unroll
  for (int kf = 0; kf < 2; ++kf)
    ash[kf] = *reinterpret_cast<const short8*>(
        kw + 32768 + (w * 16 + l15) * 64 + kf * 32 + lg * 8);

  int ch0 = w * 16 + lg * 4;
  f32x4 bo = *reinterpret_cast<const f32x4*>(bias + 256 + ch0);
  f32x4 bs = *reinterpret_cast<const f32x4*>(bias + 320 + ch0);

#pragma unroll
  for (int nt = 0; nt < 4; ++nt) {
    int p = nt * 16 + l15;
    f32x4 acc = zero;
#pragma unroll
    for (int kf = 0; kf < 4; ++kf) {
      short8 bb = *reinterpret_cast<const short8*>(&h2[h_idx(p, kf * 32 + lg * 8)]);
      acc = mfma16(a3[kf], bb, acc);
    }
#pragma unroll
    for (int kf = 0; kf < 2; ++kf) {
      short8 bb = *reinterpret_cast<const short8*>(
          xw + (kf * 4 + lg) * 512 + (nt * 16 + l15) * 8);
      acc = mfma16(ash[kf], bb, acc);
    }
#pragma unroll
    for (int jj = 0; jj < 4; ++jj) {
      int ch = ch0 + jj;
      sout[(ch << 6) | (p ^ ((ch & 7) << 3))] = acc[jj] + bo[jj] + bs[jj];
    }
  }
  __syncthreads();

  // ---- store pass: 4 rows x 256B contiguous per instruction, NT ----
  float* outp = out + (((size_t)b * 64) << 14) + pos0;
#pragma unroll
  for (int i = 0; i < 4; ++i) {
    int flat = i * 1024 + tid * 4;
    int ch = flat >> 6;
    int p = flat & 63;
    f32x4 v = *reinterpret_cast<const f32x4*>(
        &sout[(ch << 6) | (p ^ ((ch & 7) << 3))]);
    __builtin_nontemporal_store(v,
        reinterpret_cast<f32x4*>(outp + ((size_t)ch << 14) + p));
  }
}

extern "C" void kernel_launch(void* const* d_in, const int* in_sizes, int n_in,
                              void* d_out, int out_size, void* d_ws, size_t ws_size,
                              hipStream_t stream) {
  const float* x    = (const float*)d_in[0];
  const float* lat  = (const float*)d_in[1];
  const float* dk_w = (const float*)d_in[2];
  const float* dk_b = (const float*)d_in[3];
  const float* l1w1 = (const float*)d_in[4];
  const float* l1b1 = (const float*)d_in[5];
  const float* l1w2 = (const float*)d_in[6];
  const float* l1b2 = (const float*)d_in[7];
  const float* l2w1 = (const float*)d_in[8];
  const float* l2b1 = (const float*)d_in[9];
  const float* l2w2 = (const float*)d_in[10];
  const float* l2b2 = (const float*)d_in[11];
  const float* l2ws = (const float*)d_in[12];
  float* out = (float*)d_out;
  float* wsf = (float*)d_ws;

  float* h0  = wsf;                          // 8192 f32
  float* t1  = wsf + 8192;                   // 16384 f32
  float* h   = wsf + 24576;                  // 8192 f32
  float* ksv = wsf + 32768;                  // 595968 f32
  short* hxT = (short*)(wsf + 628736);       // 16*1536 bf16
  short* kwb = hxT + 24576;                  // 16*N_KW bf16
  short* xTw = kwb + (size_t)16 * N_KW;      // 16*256*4096 bf16 (33.5 MB)

  k_h0<<<dim3(2, 16), 256, 0, stream>>>(lat, dk_w, dk_b, h0);
  k_t1<<<dim3(4, 16), 256, 0, stream>>>(h0, l1w1, l1b1, t1);
  k_h <<<dim3(2, 16), 256, 0, stream>>>(h0, t1, l1w2, l1b2, h, hxT);
  k_t2<<<dim3(4, 16), 256, 0, stream>>>(h, l2w1, l2b1, hxT);
  k5_fused<<<dim3(K5_BLOCKS + XP_BLOCKS), 256, 0, stream>>>(
      l2ws, l2w2, hxT, l2b2, x, ksv, kwb, xTw);
  k_dyna<<<dim3(4096), 256, 0, stream>>>(xTw, kwb, ksv, out);
}

// Round 18
// 213.654 us; speedup vs baseline: 1.1126x; 1.1126x over previous
//
#include <hip/hip_runtime.h>

#define N_KSV 37248
#define N_KW  36864

typedef float f32x4 __attribute__((ext_vector_type(4)));
typedef short short8 __attribute__((ext_vector_type(8)));
typedef short short4v __attribute__((ext_vector_type(4)));
typedef __bf16 bf16x8 __attribute__((ext_vector_type(8)));

__device__ inline short f2bs(float f) {
  unsigned u = __builtin_bit_cast(unsigned, f);
  u += 0x7fffu + ((u >> 16) & 1u);
  return (short)(u >> 16);
}

__device__ inline f32x4 mfma16(short8 a, short8 b, f32x4 c) {
  return __builtin_amdgcn_mfma_f32_16x16x32_bf16(
      __builtin_bit_cast(bf16x8, a), __builtin_bit_cast(bf16x8, b), c, 0, 0, 0);
}

// ---------------- hypernet small chain (fp32) ----------------
__global__ void k_h0(const float* __restrict__ lat, const float* __restrict__ w,
                     const float* __restrict__ bias, float* __restrict__ h0) {
  int j = blockIdx.x * 256 + threadIdx.x;   // < 512
  int b = blockIdx.y;
  const float* lp = lat + b * 512;
  float acc = bias[j];
#pragma unroll 16
  for (int k = 0; k < 512; ++k) acc = fmaf(lp[k], w[k * 512 + j], acc);
  h0[b * 512 + j] = acc;
}

__global__ void k_t1(const float* __restrict__ h0, const float* __restrict__ w,
                     const float* __restrict__ bias, float* __restrict__ t1) {
  int j = blockIdx.x * 256 + threadIdx.x;   // < 1024
  int b = blockIdx.y;
  const float* hp = h0 + b * 512;
  float acc = bias[j];
#pragma unroll 16
  for (int k = 0; k < 512; ++k) acc = fmaf(hp[k], w[k * 1024 + j], acc);
  t1[b * 1024 + j] = fmaxf(acc, 0.f);
}

// writes hxT bf16 [16 batches][1536 k] rows 0..511 (the A operand of k5_mfma)
__global__ void k_h(const float* __restrict__ h0, const float* __restrict__ t1,
                    const float* __restrict__ w, const float* __restrict__ bias,
                    float* __restrict__ h, short* __restrict__ hxT) {
  int j = blockIdx.x * 256 + threadIdx.x;   // < 512
  int b = blockIdx.y;
  const float* tp = t1 + b * 1024;
  float acc = bias[j];
#pragma unroll 16
  for (int k = 0; k < 1024; ++k) acc = fmaf(tp[k], w[k * 512 + j], acc);
  float v = acc + h0[b * 512 + j];
  h[b * 512 + j] = v;
  hxT[b * 1536 + j] = f2bs(v);
}

__global__ void k_t2(const float* __restrict__ h, const float* __restrict__ w,
                     const float* __restrict__ bias, short* __restrict__ hxT) {
  int j = blockIdx.x * 256 + threadIdx.x;   // < 1024
  int b = blockIdx.y;
  const float* hp = h + b * 512;
  float acc = bias[j];
#pragma unroll 16
  for (int k = 0; k < 512; ++k) acc = fmaf(hp[k], w[k * 1024 + j], acc);
  hxT[b * 1536 + 512 + j] = f2bs(fmaxf(acc, 0.f));   // rows 512..1535
}

// ---------------- fat GEMM via MFMA (at the measured d_in-read floor: 229MB @ ~2.4TB/s) --------
#define LOADB(dst, ktv) { \
    const float* bp_ = ((ktv) < 16) ? (wsp + (size_t)((ktv) * 32) * N_KSV) \
                                    : (w2p + (size_t)((ktv) * 32 - 512) * N_KSV); \
    dst[0] = *reinterpret_cast<const f32x4*>(bp_); \
    dst[1] = *reinterpret_cast<const f32x4*>(bp_ + (size_t)1 * N_KSV); \
    dst[2] = *reinterpret_cast<const f32x4*>(bp_ + (size_t)2 * N_KSV); \
    dst[3] = *reinterpret_cast<const f32x4*>(bp_ + (size_t)3 * N_KSV); \
    dst[4] = *reinterpret_cast<const f32x4*>(bp_ + (size_t)4 * N_KSV); \
    dst[5] = *reinterpret_cast<const f32x4*>(bp_ + (size_t)5 * N_KSV); \
    dst[6] = *reinterpret_cast<const f32x4*>(bp_ + (size_t)6 * N_KSV); \
    dst[7] = *reinterpret_cast<const f32x4*>(bp_ + (size_t)7 * N_KSV); }

#define LOADA(dst, ktv) \
    dst = *reinterpret_cast<const short8*>(apb + (ktv) * 32);

#define COMPUTE(bsrc, asrc) { \
    _Pragma("unroll") \
    for (int t = 0; t < 4; ++t) { \
      short8 bf_; \
      bf_[0] = f2bs(bsrc[0][t]); bf_[1] = f2bs(bsrc[1][t]); \
      bf_[2] = f2bs(bsrc[2][t]); bf_[3] = f2bs(bsrc[3][t]); \
      bf_[4] = f2bs(bsrc[4][t]); bf_[5] = f2bs(bsrc[5][t]); \
      bf_[6] = f2bs(bsrc[6][t]); bf_[7] = f2bs(bsrc[7][t]); \
      acc[t] = mfma16(asrc, bf_, acc[t]); \
    } }

__global__ __launch_bounds__(256, 4) void k5_mfma(
    const float* __restrict__ wsm, const float* __restrict__ w2,
    const short* __restrict__ hxT, const float* __restrict__ b2,
    float* __restrict__ ksv, short* __restrict__ kwb) {
  __shared__ f32x4 red[3][64][4];
  const int tid = threadIdx.x;
  const int wv = tid >> 6;         // wave 0..3: kt in [wv*12, wv*12+12)
  const int lane = tid & 63;
  const int col0 = blockIdx.x * 64;
  const int l15 = lane & 15;
  const int lg = lane >> 4;

  const float* wsp = wsm + (size_t)(lg * 8) * N_KSV + col0 + l15 * 4;
  const float* w2p = w2 + (size_t)(lg * 8) * N_KSV + col0 + l15 * 4;
  const short* apb = hxT + l15 * 1536 + lg * 8;

  f32x4 acc[4];
#pragma unroll
  for (int t = 0; t < 4; ++t) acc[t] = (f32x4){0.f, 0.f, 0.f, 0.f};

  const int kt0 = wv * 12;
  f32x4 bA[8], bB[8];
  short8 aA, aB;
  LOADB(bA, kt0);
  LOADA(aA, kt0);

#pragma unroll
  for (int s = 0; s < 12; ++s) {
    if (s + 1 < 12) {
      if ((s & 1) == 0) {
        LOADB(bB, kt0 + s + 1);
        LOADA(aB, kt0 + s + 1);
      } else {
        LOADB(bA, kt0 + s + 1);
        LOADA(aA, kt0 + s + 1);
      }
    }
    if ((s & 1) == 0) COMPUTE(bA, aA) else COMPUTE(bB, aB)
  }

  if (wv > 0) {
#pragma unroll
    for (int t = 0; t < 4; ++t) red[wv - 1][lane][t] = acc[t];
  }
  __syncthreads();
  if (wv != 0) return;

#pragma unroll
  for (int t = 0; t < 4; ++t) {
    acc[t] += red[0][lane][t];
    acc[t] += red[1][lane][t];
    acc[t] += red[2][lane][t];
  }

  const int m0 = lg * 4;
#pragma unroll
  for (int t = 0; t < 4; ++t) {
    const int col = col0 + l15 * 4 + t;
    const float bias = b2[col];
#pragma unroll
    for (int r = 0; r < 4; ++r) {
      float s = acc[t][r] + bias;
      ksv[(size_t)(m0 + r) * N_KSV + col] = s;
      if (col < N_KW)
        kwb[(size_t)(m0 + r) * N_KW + col] = f2bs(s);
    }
  }
}

// ---------------- fused dyna block: 32-pos tiles for occupancy ----------------
// k_dyna is latency-bound (R15/R17: MfmaUtil 7.6%, VALU 15%, HBM 21%, occ 18%;
// halving its reads changed nothing). Fix = 2x resident waves: 20 KB LDS
// (8 blocks/CU) + launch_bounds-forced VGPR<=64 (8 waves/SIMD) -> 32 waves/CU.
__device__ inline int xT_idx(int p, int c) {
  return p * 64 + ((((c >> 3) ^ (p & 7)) << 3) | (c & 7));
}
__device__ inline int h_idx(int p, int c) {
  return p * 128 + ((((c >> 3) ^ (p & 7)) << 3) | (c & 7));
}

__global__ __launch_bounds__(256, 8) void k_dyna(const float* __restrict__ x,
                                                 const short* __restrict__ kwb,
                                                 const float* __restrict__ ksv,
                                                 float* __restrict__ out) {
  // xT: [32 pos][64 ch] (4 KB) | h1: [32][128] (8 KB) | h2: [32][128] (8 KB)
  __shared__ __align__(16) short lds[10240];
  short* xT = lds;
  short* h1 = lds + 2048;
  short* h2 = lds + 6144;
  float* sout = reinterpret_cast<float*>(h1);  // 8 KB; h1 dead after layer 2

  const int tid = threadIdx.x;
  const int lane = tid & 63;
  const int w = tid >> 6;        // wave 0..3
  const int l15 = lane & 15;
  const int lg = lane >> 4;      // 0..3

  const int b = blockIdx.x >> 9;
  const int tg = blockIdx.x & 511;
  const int pos0 = tg << 5;      // 32-pos tile

  const float* xb = x + ((size_t)b << 20) + pos0;
  const short* kw = kwb + b * N_KW;
  const float* bias = ksv + (size_t)b * N_KSV + N_KW;   // b_in|b_mid|b_out|b_sh

  // ---- stage x tile -> xT (bf16, transposed, swizzled; NT loads) ----
  // per wave-instr: 2 channel rows x 128 B contiguous.
#pragma unroll
  for (int i = 0; i < 4; ++i) {
    int cp = i * 8 + w * 2 + (lane >> 5);   // 0..31
    int p = lane & 31;
    int c = cp * 2;
    float v0 = __builtin_nontemporal_load(xb + (size_t)c * 16384 + p);
    float v1 = __builtin_nontemporal_load(xb + (size_t)(c + 1) * 16384 + p);
    int pk = (int)(unsigned short)f2bs(v0) | ((int)f2bs(v1) << 16);
    *reinterpret_cast<int*>(&xT[xT_idx(p, c)]) = pk;
  }
  __syncthreads();

  f32x4 zero = {0.f, 0.f, 0.f, 0.f};

  // ---- layer 1: h1 = relu(Kin(128x64) @ x + b_in); wave w -> ch-tiles 2w,2w+1 ----
#pragma unroll
  for (int ctl = 0; ctl < 2; ++ctl) {
    int ct = w * 2 + ctl;
    short8 a10 = *reinterpret_cast<const short8*>(kw + (ct * 16 + l15) * 64 + lg * 8);
    short8 a11 = *reinterpret_cast<const short8*>(kw + (ct * 16 + l15) * 64 + 32 + lg * 8);
    int ch0 = ct * 16 + lg * 4;
    f32x4 bv = *reinterpret_cast<const f32x4*>(bias + ch0);
#pragma unroll
    for (int nt = 0; nt < 2; ++nt) {
      int p = nt * 16 + l15;
      short8 b0 = *reinterpret_cast<const short8*>(&xT[xT_idx(p, lg * 8)]);
      short8 b1 = *reinterpret_cast<const short8*>(&xT[xT_idx(p, 32 + lg * 8)]);
      f32x4 acc = mfma16(a10, b0, zero);
      acc = mfma16(a11, b1, acc);
      short4v hv;
#pragma unroll
      for (int jj = 0; jj < 4; ++jj)
        hv[jj] = f2bs(fmaxf(acc[jj] + bv[jj], 0.f));
      *reinterpret_cast<short4v*>(&h1[h_idx(p, ch0)]) = hv;
    }
  }
  __syncthreads();

  // ---- layer 2: h2 = relu(Kmid(128x128) @ h1 + b_mid) ----
#pragma unroll
  for (int ctl = 0; ctl < 2; ++ctl) {
    int ct = w * 2 + ctl;
    short8 a2[4];
#pragma unroll
    for (int kf = 0; kf < 4; ++kf)
      a2[kf] = *reinterpret_cast<const short8*>(
          kw + 8192 + (ct * 16 + l15) * 128 + kf * 32 + lg * 8);
    int ch0 = ct * 16 + lg * 4;
    f32x4 bv = *reinterpret_cast<const f32x4*>(bias + 128 + ch0);
#pragma unroll
    for (int nt = 0; nt < 2; ++nt) {
      int p = nt * 16 + l15;
      f32x4 acc = zero;
#pragma unroll
      for (int kf = 0; kf < 4; ++kf) {
        short8 bb = *reinterpret_cast<const short8*>(&h1[h_idx(p, kf * 32 + lg * 8)]);
        acc = mfma16(a2[kf], bb, acc);
      }
      short4v hv;
#pragma unroll
      for (int jj = 0; jj < 4; ++jj)
        hv[jj] = f2bs(fmaxf(acc[jj] + bv[jj], 0.f));
      *reinterpret_cast<short4v*>(&h2[h_idx(p, ch0)]) = hv;
    }
  }
  __syncthreads();
  // h1 fully consumed -> sout may overwrite it.

  // ---- layer 3: out = Kout(64x128) @ h2 + Ksh(64x64) @ x + biases -> sout ----
  {
    short8 a3[4], ash[2];
#pragma unroll
    for (int kf = 0; kf < 4; ++kf)
      a3[kf] = *reinterpret_cast<const short8*>(
          kw + 24576 + (w * 16 + l15) * 128 + kf * 32 + lg * 8);
#pragma unroll
    for (int kf = 0; kf < 2; ++kf)
      ash[kf] = *reinterpret_cast<const short8*>(
          kw + 32768 + (w * 16 + l15) * 64 + kf * 32 + lg * 8);

    int ch0 = w * 16 + lg * 4;
    f32x4 bo = *reinterpret_cast<const f32x4*>(bias + 256 + ch0);
    f32x4 bs = *reinterpret_cast<const f32x4*>(bias + 320 + ch0);

#pragma unroll
    for (int nt = 0; nt < 2; ++nt) {
      int p = nt * 16 + l15;
      f32x4 acc = zero;
#pragma unroll
      for (int kf = 0; kf < 4; ++kf) {
        short8 bb = *reinterpret_cast<const short8*>(&h2[h_idx(p, kf * 32 + lg * 8)]);
        acc = mfma16(a3[kf], bb, acc);
      }
#pragma unroll
      for (int kf = 0; kf < 2; ++kf) {
        short8 bb = *reinterpret_cast<const short8*>(&xT[xT_idx(p, kf * 32 + lg * 8)]);
        acc = mfma16(ash[kf], bb, acc);
      }
#pragma unroll
      for (int jj = 0; jj < 4; ++jj) {
        int ch = ch0 + jj;
        sout[(ch << 5) | (p ^ ((ch & 7) << 2))] = acc[jj] + bo[jj] + bs[jj];
      }
    }
  }
  __syncthreads();

  // ---- store pass: NT f32x4, 128B-contiguous row chunks ----
  float* outp = out + (((size_t)b * 64) << 14) + pos0;
#pragma unroll
  for (int i = 0; i < 2; ++i) {
    int flat = i * 1024 + tid * 4;
    int ch = flat >> 5;
    int p = flat & 31;
    f32x4 v = *reinterpret_cast<const f32x4*>(
        &sout[(ch << 5) | (p ^ ((ch & 7) << 2))]);
    __builtin_nontemporal_store(v,
        reinterpret_cast<f32x4*>(outp + ((size_t)ch << 14) + p));
  }
}

extern "C" void kernel_launch(void* const* d_in, const int* in_sizes, int n_in,
                              void* d_out, int out_size, void* d_ws, size_t ws_size,
                              hipStream_t stream) {
  const float* x    = (const float*)d_in[0];
  const float* lat  = (const float*)d_in[1];
  const float* dk_w = (const float*)d_in[2];
  const float* dk_b = (const float*)d_in[3];
  const float* l1w1 = (const float*)d_in[4];
  const float* l1b1 = (const float*)d_in[5];
  const float* l1w2 = (const float*)d_in[6];
  const float* l1b2 = (const float*)d_in[7];
  const float* l2w1 = (const float*)d_in[8];
  const float* l2b1 = (const float*)d_in[9];
  const float* l2w2 = (const float*)d_in[10];
  const float* l2b2 = (const float*)d_in[11];
  const float* l2ws = (const float*)d_in[12];
  float* out = (float*)d_out;
  float* wsf = (float*)d_ws;

  float* h0  = wsf;                          // 8192 f32
  float* t1  = wsf + 8192;                   // 16384 f32
  float* h   = wsf + 24576;                  // 8192 f32
  float* ksv = wsf + 32768;                  // 595968 f32
  short* hxT = (short*)(wsf + 628736);       // 16*1536 bf16 (A operand, [m][k])
  short* kwb = hxT + 24576;                  // 16*N_KW bf16

  k_h0<<<dim3(2, 16), 256, 0, stream>>>(lat, dk_w, dk_b, h0);
  k_t1<<<dim3(4, 16), 256, 0, stream>>>(h0, l1w1, l1b1, t1);
  k_h <<<dim3(2, 16), 256, 0, stream>>>(h0, t1, l1w2, l1b2, h, hxT);
  k_t2<<<dim3(4, 16), 256, 0, stream>>>(h, l2w1, l2b1, hxT);
  k5_mfma<<<dim3(N_KSV / 64), 256, 0, stream>>>(l2ws, l2w2, hxT, l2b2, ksv, kwb);
  k_dyna<<<dim3(8192), 256, 0, stream>>>(x, kwb, ksv, out);
}

// Round 19
// 185.816 us; speedup vs baseline: 1.2793x; 1.1498x over previous
//
#include <hip/hip_runtime.h>

#define N_KSV 37248
#define N_KW  36864

typedef float f32x4 __attribute__((ext_vector_type(4)));
typedef short short8 __attribute__((ext_vector_type(8)));
typedef short short4v __attribute__((ext_vector_type(4)));
typedef __bf16 bf16x8 __attribute__((ext_vector_type(8)));

__device__ inline short f2bs(float f) {
  unsigned u = __builtin_bit_cast(unsigned, f);
  u += 0x7fffu + ((u >> 16) & 1u);
  return (short)(u >> 16);
}

__device__ inline f32x4 mfma16(short8 a, short8 b, f32x4 c) {
  return __builtin_amdgcn_mfma_f32_16x16x32_bf16(
      __builtin_bit_cast(bf16x8, a), __builtin_bit_cast(bf16x8, b), c, 0, 0, 0);
}

// ---------------- hypernet small chain (fp32) ----------------
__global__ void k_h0(const float* __restrict__ lat, const float* __restrict__ w,
                     const float* __restrict__ bias, float* __restrict__ h0) {
  int j = blockIdx.x * 256 + threadIdx.x;   // < 512
  int b = blockIdx.y;
  const float* lp = lat + b * 512;
  float acc = bias[j];
#pragma unroll 16
  for (int k = 0; k < 512; ++k) acc = fmaf(lp[k], w[k * 512 + j], acc);
  h0[b * 512 + j] = acc;
}

__global__ void k_t1(const float* __restrict__ h0, const float* __restrict__ w,
                     const float* __restrict__ bias, float* __restrict__ t1) {
  int j = blockIdx.x * 256 + threadIdx.x;   // < 1024
  int b = blockIdx.y;
  const float* hp = h0 + b * 512;
  float acc = bias[j];
#pragma unroll 16
  for (int k = 0; k < 512; ++k) acc = fmaf(hp[k], w[k * 1024 + j], acc);
  t1[b * 1024 + j] = fmaxf(acc, 0.f);
}

// writes hxT bf16 [16 batches][1536 k] rows 0..511 (the A operand of k5_mfma)
__global__ void k_h(const float* __restrict__ h0, const float* __restrict__ t1,
                    const float* __restrict__ w, const float* __restrict__ bias,
                    float* __restrict__ h, short* __restrict__ hxT) {
  int j = blockIdx.x * 256 + threadIdx.x;   // < 512
  int b = blockIdx.y;
  const float* tp = t1 + b * 1024;
  float acc = bias[j];
#pragma unroll 16
  for (int k = 0; k < 1024; ++k) acc = fmaf(tp[k], w[k * 512 + j], acc);
  float v = acc + h0[b * 512 + j];
  h[b * 512 + j] = v;
  hxT[b * 1536 + j] = f2bs(v);
}

__global__ void k_t2(const float* __restrict__ h, const float* __restrict__ w,
                     const float* __restrict__ bias, short* __restrict__ hxT) {
  int j = blockIdx.x * 256 + threadIdx.x;   // < 1024
  int b = blockIdx.y;
  const float* hp = h + b * 512;
  float acc = bias[j];
#pragma unroll 16
  for (int k = 0; k < 512; ++k) acc = fmaf(hp[k], w[k * 1024 + j], acc);
  hxT[b * 1536 + 512 + j] = f2bs(fmaxf(acc, 0.f));   // rows 512..1535
}

// ---------------- fat GEMM via MFMA (at the measured d_in-read floor: 229MB @ ~2.4TB/s) --------
#define LOADB(dst, ktv) { \
    const float* bp_ = ((ktv) < 16) ? (wsp + (size_t)((ktv) * 32) * N_KSV) \
                                    : (w2p + (size_t)((ktv) * 32 - 512) * N_KSV); \
    dst[0] = *reinterpret_cast<const f32x4*>(bp_); \
    dst[1] = *reinterpret_cast<const f32x4*>(bp_ + (size_t)1 * N_KSV); \
    dst[2] = *reinterpret_cast<const f32x4*>(bp_ + (size_t)2 * N_KSV); \
    dst[3] = *reinterpret_cast<const f32x4*>(bp_ + (size_t)3 * N_KSV); \
    dst[4] = *reinterpret_cast<const f32x4*>(bp_ + (size_t)4 * N_KSV); \
    dst[5] = *reinterpret_cast<const f32x4*>(bp_ + (size_t)5 * N_KSV); \
    dst[6] = *reinterpret_cast<const f32x4*>(bp_ + (size_t)6 * N_KSV); \
    dst[7] = *reinterpret_cast<const f32x4*>(bp_ + (size_t)7 * N_KSV); }

#define LOADA(dst, ktv) \
    dst = *reinterpret_cast<const short8*>(apb + (ktv) * 32);

#define COMPUTE(bsrc, asrc) { \
    _Pragma("unroll") \
    for (int t = 0; t < 4; ++t) { \
      short8 bf_; \
      bf_[0] = f2bs(bsrc[0][t]); bf_[1] = f2bs(bsrc[1][t]); \
      bf_[2] = f2bs(bsrc[2][t]); bf_[3] = f2bs(bsrc[3][t]); \
      bf_[4] = f2bs(bsrc[4][t]); bf_[5] = f2bs(bsrc[5][t]); \
      bf_[6] = f2bs(bsrc[6][t]); bf_[7] = f2bs(bsrc[7][t]); \
      acc[t] = mfma16(asrc, bf_, acc[t]); \
    } }

__global__ __launch_bounds__(256, 4) void k5_mfma(
    const float* __restrict__ wsm, const float* __restrict__ w2,
    const short* __restrict__ hxT, const float* __restrict__ b2,
    float* __restrict__ ksv, short* __restrict__ kwb) {
  __shared__ f32x4 red[3][64][4];
  const int tid = threadIdx.x;
  const int wv = tid >> 6;         // wave 0..3: kt in [wv*12, wv*12+12)
  const int lane = tid & 63;
  const int col0 = blockIdx.x * 64;
  const int l15 = lane & 15;
  const int lg = lane >> 4;

  const float* wsp = wsm + (size_t)(lg * 8) * N_KSV + col0 + l15 * 4;
  const float* w2p = w2 + (size_t)(lg * 8) * N_KSV + col0 + l15 * 4;
  const short* apb = hxT + l15 * 1536 + lg * 8;

  f32x4 acc[4];
#pragma unroll
  for (int t = 0; t < 4; ++t) acc[t] = (f32x4){0.f, 0.f, 0.f, 0.f};

  const int kt0 = wv * 12;
  f32x4 bA[8], bB[8];
  short8 aA, aB;
  LOADB(bA, kt0);
  LOADA(aA, kt0);

#pragma unroll
  for (int s = 0; s < 12; ++s) {
    if (s + 1 < 12) {
      if ((s & 1) == 0) {
        LOADB(bB, kt0 + s + 1);
        LOADA(aB, kt0 + s + 1);
      } else {
        LOADB(bA, kt0 + s + 1);
        LOADA(aA, kt0 + s + 1);
      }
    }
    if ((s & 1) == 0) COMPUTE(bA, aA) else COMPUTE(bB, aB)
  }

  if (wv > 0) {
#pragma unroll
    for (int t = 0; t < 4; ++t) red[wv - 1][lane][t] = acc[t];
  }
  __syncthreads();
  if (wv != 0) return;

#pragma unroll
  for (int t = 0; t < 4; ++t) {
    acc[t] += red[0][lane][t];
    acc[t] += red[1][lane][t];
    acc[t] += red[2][lane][t];
  }

  const int m0 = lg * 4;
#pragma unroll
  for (int t = 0; t < 4; ++t) {
    const int col = col0 + l15 * 4 + t;
    const float bias = b2[col];
#pragma unroll
    for (int r = 0; r < 4; ++r) {
      float s = acc[t][r] + bias;
      ksv[(size_t)(m0 + r) * N_KSV + col] = s;
      if (col < N_KW)
        kwb[(size_t)(m0 + r) * N_KW + col] = f2bs(s);
    }
  }
}

// ---------------- fused dyna block: 4 x (1x1 conv) via bf16 MFMA ----------------
// Best-measured variant (R16, 189.9us total): NT x-loads, MFMA layers from
// swizzled LDS, write-combined epilogue (LDS-staged, 256B-contiguous NT f32x4).
__device__ inline int xT_idx(int p, int c) {
  return p * 64 + ((((c >> 3) ^ (p & 7)) << 3) | (c & 7));
}
__device__ inline int h_idx(int p, int c) {
  return p * 128 + ((((c >> 3) ^ (p & 7)) << 3) | (c & 7));
}

__global__ __launch_bounds__(256) void k_dyna(const float* __restrict__ x,
                                              const short* __restrict__ kwb,
                                              const float* __restrict__ ksv,
                                              float* __restrict__ out) {
  __shared__ __align__(16) short lds[20480];  // xT:0..4095  h1:4096..12287  h2:12288..20479
  short* xT = lds;
  short* h1 = lds + 4096;
  short* h2 = lds + 12288;
  float* sout = reinterpret_cast<float*>(h1);  // 16 KB; h1 is dead after layer 2

  const int tid = threadIdx.x;
  const int lane = tid & 63;
  const int w = tid >> 6;        // wave 0..3
  const int l15 = lane & 15;
  const int lg = lane >> 4;      // 0..3

  const int b = blockIdx.x >> 8;
  const int pos0 = (blockIdx.x & 255) << 6;

  const float* xb = x + ((size_t)b << 20) + pos0;           // x[b][.][pos0+.]
  const short* kw = kwb + b * N_KW;
  const float* bias = ksv + (size_t)b * N_KSV + N_KW;       // b_in | b_mid | b_out | b_sh

  // ---- stage x tile -> xT (bf16, transposed, swizzled; nt loads) ----
#pragma unroll
  for (int i = 0; i < 8; ++i) {
    int p = lane;
    int cp = i * 4 + w;          // 0..31
    int c = cp * 2;
    float v0 = __builtin_nontemporal_load(xb + (size_t)c * 16384 + p);
    float v1 = __builtin_nontemporal_load(xb + (size_t)(c + 1) * 16384 + p);
    int idx = xT_idx(p, c);      // even; packs c, c+1
    int pk = (int)(unsigned short)f2bs(v0) | ((int)f2bs(v1) << 16);
    *reinterpret_cast<int*>(&xT[idx]) = pk;
  }
  __syncthreads();

  // ---- layer 1: h1 = relu(Kin(128x64) @ x + b_in) ----
  short8 a1[2][2];
#pragma unroll
  for (int mt = 0; mt < 2; ++mt)
#pragma unroll
    for (int kf = 0; kf < 2; ++kf)
      a1[mt][kf] = *reinterpret_cast<const short8*>(
          kw + (w * 32 + mt * 16 + l15) * 64 + kf * 32 + lg * 8);

  f32x4 zero = {0.f, 0.f, 0.f, 0.f};
  f32x4 acc1[2][4];
#pragma unroll
  for (int mt = 0; mt < 2; ++mt)
#pragma unroll
    for (int nt = 0; nt < 4; ++nt) acc1[mt][nt] = zero;

#pragma unroll
  for (int nt = 0; nt < 4; ++nt) {
    int p = nt * 16 + l15;
    short8 b0 = *reinterpret_cast<const short8*>(&xT[xT_idx(p, lg * 8)]);
    short8 b1 = *reinterpret_cast<const short8*>(&xT[xT_idx(p, 32 + lg * 8)]);
#pragma unroll
    for (int mt = 0; mt < 2; ++mt) {
      acc1[mt][nt] = mfma16(a1[mt][0], b0, acc1[mt][nt]);
      acc1[mt][nt] = mfma16(a1[mt][1], b1, acc1[mt][nt]);
    }
  }
#pragma unroll
  for (int mt = 0; mt < 2; ++mt) {
    int ch0 = w * 32 + mt * 16 + lg * 4;
    f32x4 bv = *reinterpret_cast<const f32x4*>(bias + ch0);
#pragma unroll
    for (int nt = 0; nt < 4; ++nt) {
      int p = nt * 16 + l15;
      short4v hv;
#pragma unroll
      for (int jj = 0; jj < 4; ++jj)
        hv[jj] = f2bs(fmaxf(acc1[mt][nt][jj] + bv[jj], 0.f));
      *reinterpret_cast<short4v*>(&h1[h_idx(p, ch0)]) = hv;
    }
  }
  __syncthreads();

  // ---- layer 2: h2 = relu(Kmid(128x128) @ h1 + b_mid) ----
  short8 a2[2][4];
#pragma unroll
  for (int mt = 0; mt < 2; ++mt)
#pragma unroll
    for (int kf = 0; kf < 4; ++kf)
      a2[mt][kf] = *reinterpret_cast<const short8*>(
          kw + 8192 + (w * 32 + mt * 16 + l15) * 128 + kf * 32 + lg * 8);

  f32x4 acc2[2][4];
#pragma unroll
  for (int mt = 0; mt < 2; ++mt)
#pragma unroll
    for (int nt = 0; nt < 4; ++nt) acc2[mt][nt] = zero;

#pragma unroll
  for (int nt = 0; nt < 4; ++nt) {
    int p = nt * 16 + l15;
    short8 bb[4];
#pragma unroll
    for (int kf = 0; kf < 4; ++kf)
      bb[kf] = *reinterpret_cast<const short8*>(&h1[h_idx(p, kf * 32 + lg * 8)]);
#pragma unroll
    for (int mt = 0; mt < 2; ++mt)
#pragma unroll
      for (int kf = 0; kf < 4; ++kf)
        acc2[mt][nt] = mfma16(a2[mt][kf], bb[kf], acc2[mt][nt]);
  }
#pragma unroll
  for (int mt = 0; mt < 2; ++mt) {
    int ch0 = w * 32 + mt * 16 + lg * 4;
    f32x4 bv = *reinterpret_cast<const f32x4*>(bias + 128 + ch0);
#pragma unroll
    for (int nt = 0; nt < 4; ++nt) {
      int p = nt * 16 + l15;
      short4v hv;
#pragma unroll
      for (int jj = 0; jj < 4; ++jj)
        hv[jj] = f2bs(fmaxf(acc2[mt][nt][jj] + bv[jj], 0.f));
      *reinterpret_cast<short4v*>(&h2[h_idx(p, ch0)]) = hv;
    }
  }
  __syncthreads();
  // NOTE: h1 fully consumed above (reads precede this barrier) -> sout may
  // overwrite it in layer 3.

  // ---- layer 3: acc = Kout(64x128) @ h2 + Ksh(64x64) @ x + biases -> sout ----
  short8 a3[4], ash[2];
#pragma unroll
  for (int kf = 0; kf < 4; ++kf)
    a3[kf] = *reinterpret_cast<const short8*>(
        kw + 24576 + (w * 16 + l15) * 128 + kf * 32 + lg * 8);
#pragma unroll
  for (int kf = 0; kf < 2; ++kf)
    ash[kf] = *reinterpret_cast<const short8*>(
        kw + 32768 + (w * 16 + l15) * 64 + kf * 32 + lg * 8);

  int ch0 = w * 16 + lg * 4;
  f32x4 bo = *reinterpret_cast<const f32x4*>(bias + 256 + ch0);
  f32x4 bs = *reinterpret_cast<const f32x4*>(bias + 320 + ch0);

#pragma unroll
  for (int nt = 0; nt < 4; ++nt) {
    int p = nt * 16 + l15;
    f32x4 acc = zero;
#pragma unroll
    for (int kf = 0; kf < 4; ++kf) {
      short8 bb = *reinterpret_cast<const short8*>(&h2[h_idx(p, kf * 32 + lg * 8)]);
      acc = mfma16(a3[kf], bb, acc);
    }
#pragma unroll
    for (int kf = 0; kf < 2; ++kf) {
      short8 bb = *reinterpret_cast<const short8*>(&xT[xT_idx(p, kf * 32 + lg * 8)]);
      acc = mfma16(ash[kf], bb, acc);
    }
#pragma unroll
    for (int jj = 0; jj < 4; ++jj) {
      int ch = ch0 + jj;
      sout[(ch << 6) | (p ^ ((ch & 7) << 3))] = acc[jj] + bo[jj] + bs[jj];
    }
  }
  __syncthreads();

  // ---- store pass: per instruction, 4 rows x 256B fully contiguous ----
  float* outp = out + (((size_t)b * 64) << 14) + pos0;
#pragma unroll
  for (int i = 0; i < 4; ++i) {
    int flat = i * 1024 + tid * 4;
    int ch = flat >> 6;
    int p = flat & 63;
    f32x4 v = *reinterpret_cast<const f32x4*>(
        &sout[(ch << 6) | (p ^ ((ch & 7) << 3))]);
    __builtin_nontemporal_store(v,
        reinterpret_cast<f32x4*>(outp + ((size_t)ch << 14) + p));
  }
}

extern "C" void kernel_launch(void* const* d_in, const int* in_sizes, int n_in,
                              void* d_out, int out_size, void* d_ws, size_t ws_size,
                              hipStream_t stream) {
  const float* x    = (const float*)d_in[0];
  const float* lat  = (const float*)d_in[1];
  const float* dk_w = (const float*)d_in[2];
  const float* dk_b = (const float*)d_in[3];
  const float* l1w1 = (const float*)d_in[4];
  const float* l1b1 = (const float*)d_in[5];
  const float* l1w2 = (const float*)d_in[6];
  const float* l1b2 = (const float*)d_in[7];
  const float* l2w1 = (const float*)d_in[8];
  const float* l2b1 = (const float*)d_in[9];
  const float* l2w2 = (const float*)d_in[10];
  const float* l2b2 = (const float*)d_in[11];
  const float* l2ws = (const float*)d_in[12];
  float* out = (float*)d_out;
  float* wsf = (float*)d_ws;

  float* h0  = wsf;                          // 8192 f32
  float* t1  = wsf + 8192;                   // 16384 f32
  float* h   = wsf + 24576;                  // 8192 f32
  float* ksv = wsf + 32768;                  // 595968 f32
  short* hxT = (short*)(wsf + 628736);       // 16*1536 bf16 (A operand, [m][k])
  short* kwb = hxT + 24576;                  // 16*N_KW bf16

  k_h0<<<dim3(2, 16), 256, 0, stream>>>(lat, dk_w, dk_b, h0);
  k_t1<<<dim3(4, 16), 256, 0, stream>>>(h0, l1w1, l1b1, t1);
  k_h <<<dim3(2, 16), 256, 0, stream>>>(h0, t1, l1w2, l1b2, h, hxT);
  k_t2<<<dim3(4, 16), 256, 0, stream>>>(h, l2w1, l2b1, hxT);
  k5_mfma<<<dim3(N_KSV / 64), 256, 0, stream>>>(l2ws, l2w2, hxT, l2b2, ksv, kwb);
  k_dyna<<<dim3(4096), 256, 0, stream>>>(x, kwb, ksv, out);
}